// Round 16
// baseline (93.806 us; speedup 1.0000x reference)
//
#include <hip/hip_runtime.h>

#define B_SZ   4096
#define H_SZ   200
#define D_SZ   128
#define N_SZ   256
#define ROWS   (B_SZ * H_SZ)      // 819200
#define BM     64
#define TPB    8                  // tiles per block
#define RPB    (BM * TPB)         // 512 rows per block
#define NBLK   (ROWS / RPB)       // 1600

typedef __attribute__((ext_vector_type(8))) short bf16x8;
typedef __attribute__((ext_vector_type(4))) float f32x4;

__device__ __forceinline__ unsigned short f2bf(float f) {
    unsigned u = __builtin_bit_cast(unsigned, f);
    u += 0x7FFFu + ((u >> 16) & 1u);
    return (unsigned short)(u >> 16);
}
// pack two f32 to bf16x2 (truncate) in one v_perm_b32
__device__ __forceinline__ unsigned bfpack2(float a, float b) {
    return __builtin_amdgcn_perm(__builtin_bit_cast(unsigned, b),
                                 __builtin_bit_cast(unsigned, a), 0x07060302u);
}

// Kernel 0: W1 [128][256] f32 -> W1T [256][128] bf16 (RNE)
__global__ __launch_bounds__(256) void cvt_w1(const float* __restrict__ src,
                                              unsigned short* __restrict__ dst) {
    int i = blockIdx.x * 256 + threadIdx.x;   // i = n*128 + d
    int n = i >> 7, d = i & 127;
    dst[i] = f2bf(src[d * N_SZ + n]);
}

// Main (r7 structure): 512 thr = 8 waves; wave w owns N-cols [32w,32w+32).
// Epilogue vectorized to VOP3P packed-f32 (pk_max / pk_fma).
__global__ __launch_bounds__(512, 4) void nais_main(
    const int* __restrict__ history, const int* __restrict__ target,
    const float* __restrict__ eh, const float* __restrict__ et,
    const unsigned short* __restrict__ w1t, const float* __restrict__ b1,
    const float* __restrict__ w2,
    float* __restrict__ a_out, float* __restrict__ dotd_out)
{
    __shared__ uint4 AbufV[2][BM * 256 / 16];  // 32 KB swizzled [64][128] bf16 x2
    __shared__ float apart[2][8][BM];          // 4 KB
    __shared__ float tgt_f[4][D_SZ];           // 2 KB (f32)

    const int tid  = threadIdx.x;
    const int wid  = tid >> 6;
    const int lane = tid & 63;
    const int lo   = lane & 15;
    const int hi   = lane >> 4;
    const int row  = tid >> 3;
    const int seg  = tid & 7;
    const int blk  = blockIdx.x;
    const int b_base = (blk * RPB) / H_SZ;

    {   // preload 4 target rows (f32), direct broadcast reads
        const int r4 = tid >> 7, d = tid & 127;
        int bb = b_base + r4;
        int tg = target[bb < B_SZ ? bb : (B_SZ - 1)];
        tgt_f[r4][d] = et[(size_t)tg * D_SZ + d];
    }

    // W1T bf16 fragments: wave wid owns cols [32*wid, 32*wid+32)
    bf16x8 wfrag[4][2];
    #pragma unroll
    for (int ni = 0; ni < 2; ++ni) {
        int n = 32 * wid + 16 * ni + lo;
        #pragma unroll
        for (int ki = 0; ki < 4; ++ki)
            wfrag[ki][ni] = *(const bf16x8*)(w1t + (size_t)n * D_SZ + 32 * ki + 8 * hi);
    }
    // b1 / w2 per-lane: n = 32wid + {0,16} + 4hi + r
    const int n0 = 32 * wid + 4 * hi;
    const f32x4 b1a = *(const f32x4*)(b1 + n0);
    const f32x4 b1b = *(const f32x4*)(b1 + n0 + 16);
    const f32x4 w2a = *(const f32x4*)(w2 + n0);
    const f32x4 w2b = *(const f32x4*)(w2 + n0 + 16);

    // gather prologue: two 32B chunks per row: d in [8s,8s+8) and [64+8s,64+8s+8)
    const int grow0 = blk * RPB + row;
    const int* hrow = history + grow0;
    int ih_cur = hrow[0];
    int ih_nxt = hrow[BM];
    f32x4 hq0, hq1, hq2, hq3;
    {
        const float* base = eh + (size_t)ih_cur * D_SZ + 8 * seg;
        hq0 = *(const f32x4*)(base);      hq1 = *(const f32x4*)(base + 4);
        hq2 = *(const f32x4*)(base + 64); hq3 = *(const f32x4*)(base + 68);
    }
    int b_loc = grow0 / H_SZ - b_base;
    int rem   = grow0 - (b_loc + b_base) * H_SZ;
    __syncthreads();   // tgt_f ready

    for (int t = 0; t < TPB; ++t) {
        char* Ab = (char*)AbufV[t & 1];
        const int gr = grow0 + t * BM;

        // ---- construct tile t: pk f32 mul + exact f32 dotd + bf16 trunc pack ----
        {
            const float* tp = &tgt_f[b_loc][8 * seg];
            f32x4 t0 = *(const f32x4*)(tp);      f32x4 t1 = *(const f32x4*)(tp + 4);
            f32x4 t2 = *(const f32x4*)(tp + 64); f32x4 t3 = *(const f32x4*)(tp + 68);
            f32x4 x0 = hq0 * t0, x1 = hq1 * t1, x2 = hq2 * t2, x3 = hq3 * t3;
            f32x4 sx = (x0 + x1) + (x2 + x3);
            float s = (sx[0] + sx[1]) + (sx[2] + sx[3]);
            s += __shfl_xor(s, 1);
            s += __shfl_xor(s, 2);
            s += __shfl_xor(s, 4);
            if (seg == 0) dotd_out[gr] = s;
            uint4 o1 = uint4{bfpack2(x0[0], x0[1]), bfpack2(x0[2], x0[3]),
                             bfpack2(x1[0], x1[1]), bfpack2(x1[2], x1[3])};
            uint4 o2 = uint4{bfpack2(x2[0], x2[1]), bfpack2(x2[2], x2[3]),
                             bfpack2(x3[0], x3[1]), bfpack2(x3[2], x3[3])};
            const unsigned sw = (unsigned)((row & 7) << 4);
            char* rb = Ab + row * 256;
            *(uint4*)(rb + (((unsigned)(16 * seg)) ^ sw))          = o1;
            *(uint4*)(rb + (128u + (((unsigned)(16 * seg)) ^ sw))) = o2;
        }
        __syncthreads();   // [single barrier per tile]

        // ---- prefetch next tile's gathers (hide under MFMA) ----
        if (t + 1 < TPB) {
            ih_cur = ih_nxt;
            if (t + 2 < TPB) ih_nxt = hrow[(t + 2) * BM];
            const float* base = eh + (size_t)ih_cur * D_SZ + 8 * seg;
            hq0 = *(const f32x4*)(base);      hq1 = *(const f32x4*)(base + 4);
            hq2 = *(const f32x4*)(base + 64); hq3 = *(const f32x4*)(base + 68);
        }

        // ---- lagged reduction of tile t-1's apart ----
        if (t > 0 && tid < BM) {
            const float* ap = &apart[(t - 1) & 1][0][tid];
            float a = ap[0];
            #pragma unroll
            for (int w = 1; w < 8; ++w) a += ap[w * BM];
            a_out[blk * RPB + (t - 1) * BM + tid] = a;
        }

        // ---- swapped MFMA (bf16) + packed-f32 epilogue ----
        #pragma unroll
        for (int mi = 0; mi < 4; ++mi) {
            const int rr = 16 * mi + lo;
            const unsigned swr = (unsigned)((rr & 7) << 4);
            bf16x8 af[4];
            #pragma unroll
            for (int ki = 0; ki < 4; ++ki) {
                unsigned off = ((unsigned)(64 * ki + 16 * hi)) ^ swr;
                af[ki] = *(const bf16x8*)(Ab + rr * 256 + off);
            }
            f32x4 acc0 = b1a;   // b1 folded into accumulator init
            f32x4 acc1 = b1b;
            __builtin_amdgcn_s_setprio(1);
            #pragma unroll
            for (int ki = 0; ki < 4; ++ki) {
                acc0 = __builtin_amdgcn_mfma_f32_16x16x32_bf16(wfrag[ki][0], af[ki], acc0, 0, 0, 0);
                acc1 = __builtin_amdgcn_mfma_f32_16x16x32_bf16(wfrag[ki][1], af[ki], acc1, 0, 0, 0);
            }
            __builtin_amdgcn_s_setprio(0);
            // packed: 4 pk_max + 2 pk_mul + 2 pk_fma + 3 adds
            const f32x4 zero = {0.f, 0.f, 0.f, 0.f};
            f32x4 m0 = __builtin_elementwise_max(acc0, zero);
            f32x4 m1 = __builtin_elementwise_max(acc1, zero);
            f32x4 p  = m0 * w2a + m1 * w2b;
            float v = (p[0] + p[1]) + (p[2] + p[3]);
            v += __shfl_xor(v, 16);
            v += __shfl_xor(v, 32);
            if (lane < 16) apart[t & 1][wid][16 * mi + lane] = v;
        }

        // advance incremental b_loc (row += 64)
        rem += BM;
        if (rem >= H_SZ) { rem -= H_SZ; ++b_loc; }
    }
    __syncthreads();
    if (tid < BM) {   // final tile's reduction
        const float* ap = &apart[(TPB - 1) & 1][0][tid];
        float a = ap[0];
        #pragma unroll
        for (int w = 1; w < 8; ++w) a += ap[w * BM];
        a_out[blk * RPB + (TPB - 1) * BM + tid] = a;
    }
}

// Finish: per-b masked exp, beta=0.5 power norm, weighted dot, sigmoid
__global__ __launch_bounds__(64) void nais_finish(
    const int* __restrict__ history, const int* __restrict__ target,
    const float* __restrict__ a_in, const float* __restrict__ dotd_in,
    float* __restrict__ out)
{
    const int b    = blockIdx.x;
    const int lane = threadIdx.x;
    const int tgt  = target[b];
    float s1 = 0.f, s2 = 0.f;
    for (int h = lane; h < H_SZ; h += 64) {
        int rg = b * H_SZ + h;
        float e = (history[rg] != tgt) ? __expf(a_in[rg]) : 0.f;
        s1 += e;
        s2 += e * dotd_in[rg];
    }
    #pragma unroll
    for (int o = 1; o < 64; o <<= 1) {
        s1 += __shfl_xor(s1, o);
        s2 += __shfl_xor(s2, o);
    }
    if (lane == 0) {
        float pred = s2 / sqrtf(s1);
        out[b] = 1.f / (1.f + __expf(-pred));
    }
}

extern "C" void kernel_launch(void* const* d_in, const int* in_sizes, int n_in,
                              void* d_out, int out_size, void* d_ws, size_t ws_size,
                              hipStream_t stream) {
    const int*   history = (const int*)d_in[0];
    const int*   target  = (const int*)d_in[1];
    const float* eh      = (const float*)d_in[2];
    const float* et      = (const float*)d_in[3];
    const float* W1      = (const float*)d_in[4];
    const float* b1      = (const float*)d_in[5];
    const float* w2      = (const float*)d_in[6];
    float* out = (float*)d_out;

    char* ws = (char*)d_ws;
    unsigned short* w1t = (unsigned short*)ws;        // 64 KB bf16
    float* a_ws    = (float*)(ws + N_SZ * D_SZ * 2);
    float* dotd_ws = a_ws + ROWS;                     // 3.3 MB each

    cvt_w1<<<(N_SZ * D_SZ) / 256, 256, 0, stream>>>(W1, w1t);
    nais_main<<<NBLK, 512, 0, stream>>>(history, target, eh, et, w1t, b1, w2, a_ws, dotd_ws);
    nais_finish<<<B_SZ, 64, 0, stream>>>(history, target, a_ws, dotd_ws, out);
}